// Round 6
// baseline (659.647 us; speedup 1.0000x reference)
//
#include <hip/hip_runtime.h>
#include <hip/hip_bf16.h>
#include <math.h>

#define E_N 4096
#define PI_F 3.14159265358979323846f
#define ATH 0.08726646259971647f   /* radians(5.0) */

// angle counting-sort bins
#define AB_N 2048
#define AB_SCALE 651.8986469f      /* 2048/pi */
#define BWINP1 60                  /* window [p+1, bstart[bin+60]); ceil(ATH*scale)=57 +3 margin */

// selection histograms: coarse 8192 bins over [0,160), sub 1024 -> res 1.9e-5
#define NBH 8192
#define SCALEH 51.2f               /* NBH/160 */
#define WH 0.01953125f             /* 160/NBH exact */
#define NBS 1024
#define SCALES 52428.8f            /* NBS/WH */
#define WS2 (WH / 1024.0f)

// workspace layout (bytes); ws is ~256 MiB
#define O_UANG 0          /* unsorted per-edge: 4096 f32 each */
#define O_UNX  16384
#define O_UNY  32768
#define O_UC   49152
#define O_UMX  65536
#define O_UMY  81920
#define O_SANG 98304      /* sorted-order copies */
#define O_SNX  114688
#define O_SNY  131072
#define O_SC   147456
#define O_SMX  163840
#define O_SMY  180224
#define O_SORG 196608     /* sorted slot -> original edge idx */
#define O_BST  212992     /* 2048 u32 angle-bin starts */
#define O_CTL  221184     /* u32[0]=cursor [1]=ticket1 [2]=ticket2; f[4]=mu f[5]=margin; [8..9]=gsum(double) */
#define O_DBUF 262144     /* accepted distances, cap DBMAX floats (32MB) */
#define DBMAX  8000000u

__device__ __forceinline__ int bin_of(float a) {
    int b = (int)(a * AB_SCALE);
    return b < 0 ? 0 : (b > AB_N - 1 ? AB_N - 1 : b);
}

// ---- K1: per-edge geometry (16 x 256); zeroes control words ----------------
__global__ __launch_bounds__(256) void prep(const void* __restrict__ posv,
                                            const int* __restrict__ eidx,
                                            char* __restrict__ ws)
{
    float* uang = (float*)(ws + O_UANG);
    float* unx  = (float*)(ws + O_UNX);
    float* uny  = (float*)(ws + O_UNY);
    float* uc   = (float*)(ws + O_UC);
    float* umx  = (float*)(ws + O_UMX);
    float* umy  = (float*)(ws + O_UMY);
    unsigned* ctl = (unsigned*)(ws + O_CTL);
    int tid = threadIdx.x;
    int gid = blockIdx.x * 256 + tid;
    if (gid < 16) ctl[gid] = 0u;    // cursor/tickets/mu/margin/gsum

    // dtype detect: f32 read as bf16 halves shows exponents >=137 (|v|>=1024)
    __shared__ unsigned s_flag;
    if (tid == 0) s_flag = 0u;
    __syncthreads();
    {
        const unsigned short* ph = (const unsigned short*)posv;
        unsigned f = 0;
        for (int k = tid; k < 2 * E_N; k += 256) {
            unsigned short v = ph[k];
            if (((v >> 7) & 0xFFu) >= 137u) f = 1u;
        }
        if (f) atomicOr(&s_flag, 1u);
    }
    __syncthreads();
    bool isf32 = (s_flag != 0u);

    int s = eidx[gid], d = eidx[E_N + gid];
    float px, py, qx, qy;
    if (isf32) {
        const float* pf = (const float*)posv;
        px = pf[2*s]; py = pf[2*s+1]; qx = pf[2*d]; qy = pf[2*d+1];
    } else {
        const __hip_bfloat16* pb = (const __hip_bfloat16*)posv;
        px = __bfloat162float(pb[2*s]); py = __bfloat162float(pb[2*s+1]);
        qx = __bfloat162float(pb[2*d]); qy = __bfloat162float(pb[2*d+1]);
    }
    float vx = qx - px, vy = qy - py;
    float len = fmaxf(sqrtf(vx*vx + vy*vy), 1e-8f);
    float dx = vx / len, dy = vy / len;
    float a = fmodf(atan2f(dy, dx), PI_F);
    if (a < 0.0f) a += PI_F;          // python floor-mod -> [0, pi)
    uang[gid] = a;
    unx[gid] = -dy; uny[gid] = dx;
    uc[gid]  = px * (-dy) + py * dx;
    umx[gid] = (px + qx) * 0.5f;
    umy[gid] = (py + qy) * 0.5f;
}

// ---- K2: counting sort into sorted-order attribute arrays (1 x 1024) -------
__global__ __launch_bounds__(1024) void sortk(char* __restrict__ ws)
{
    float* uang = (float*)(ws + O_UANG);
    float* unx  = (float*)(ws + O_UNX);
    float* uny  = (float*)(ws + O_UNY);
    float* uc   = (float*)(ws + O_UC);
    float* umx  = (float*)(ws + O_UMX);
    float* umy  = (float*)(ws + O_UMY);
    float* angS = (float*)(ws + O_SANG);
    float* nxS  = (float*)(ws + O_SNX);
    float* nyS  = (float*)(ws + O_SNY);
    float* cS   = (float*)(ws + O_SC);
    float* mxS  = (float*)(ws + O_SMX);
    float* myS  = (float*)(ws + O_SMY);
    unsigned* origS = (unsigned*)(ws + O_SORG);
    unsigned* bst   = (unsigned*)(ws + O_BST);

    __shared__ unsigned cnt[AB_N];
    __shared__ unsigned scn[1024];
    int tid = threadIdx.x;
    cnt[tid] = 0u; cnt[tid + 1024] = 0u;
    __syncthreads();
    int lb[4];
#pragma unroll
    for (int k = 0; k < 4; ++k) {
        int e = tid + k * 1024;
        int b = bin_of(uang[e]);
        lb[k] = b;
        atomicAdd(&cnt[b], 1u);
    }
    __syncthreads();
    unsigned c0 = cnt[2*tid], c1 = cnt[2*tid+1], s2 = c0 + c1;
    scn[tid] = s2;
    __syncthreads();
    for (int off = 1; off < 1024; off <<= 1) {
        unsigned v = (tid >= off) ? scn[tid - off] : 0u;
        __syncthreads();
        scn[tid] += v;
        __syncthreads();
    }
    unsigned excl = scn[tid] - s2;
    bst[2*tid] = excl; bst[2*tid+1] = excl + c0;
    cnt[2*tid] = excl; cnt[2*tid+1] = excl + c0;   // reuse as cursors
    __syncthreads();
#pragma unroll
    for (int k = 0; k < 4; ++k) {
        int e = tid + k * 1024;
        unsigned pos = atomicAdd(&cnt[lb[k]], 1u);
        angS[pos] = uang[e]; nxS[pos] = unx[e]; nyS[pos] = uny[e];
        cS[pos] = uc[e]; mxS[pos] = umx[e]; myS[pos] = umy[e];
        origS[pos] = (unsigned)e;
    }
}

// ---- K3: single window sweep -> compacted dbuf; last block selects quantiles
__global__ __launch_bounds__(512) void sweep(char* __restrict__ ws)
{
    float* angS = (float*)(ws + O_SANG);
    float* nxS  = (float*)(ws + O_SNX);
    float* nyS  = (float*)(ws + O_SNY);
    float* cS   = (float*)(ws + O_SC);
    float* mxS  = (float*)(ws + O_SMX);
    float* myS  = (float*)(ws + O_SMY);
    unsigned* origS = (unsigned*)(ws + O_SORG);
    unsigned* bst   = (unsigned*)(ws + O_BST);
    unsigned* ctl   = (unsigned*)(ws + O_CTL);
    float* dbuf     = (float*)(ws + O_DBUF);

    __shared__ unsigned s_hist[NBH];     // 32KB (epilogue only)
    __shared__ unsigned s_bst[AB_N];     // 8KB
    __shared__ unsigned s_sub[3 * NBS];  // 12KB (epilogue only)
    __shared__ unsigned s_tmp[512];
    __shared__ unsigned s_info[8];       // [0..2] target bins, [3..5] rank-in-bin
    __shared__ float    s_vv[3];
    __shared__ unsigned s_last;

    int tid = threadIdx.x, bid = blockIdx.x;
    int w = tid >> 6, lane = tid & 63;
    for (int k = tid; k < AB_N; k += 512) s_bst[k] = bst[k];
    __syncthreads();

    // sweep: each of 8 waves handles 2 sorted slots; lanes stride the window
#pragma unroll 1
    for (int i = 0; i < 2; ++i) {
        int p = bid * 16 + i * 8 + w;
        float ap = angS[p];
        int bw = bin_of(ap) + BWINP1; if (bw >= AB_N) bw -= AB_N;
        unsigned wc = (s_bst[bw] + E_N - 1u - (unsigned)p) & (E_N - 1u);
        unsigned op = origS[p];
        float pnx = nxS[p], pny = nyS[p], pc = cS[p];
        float pmx = mxS[p], pmy = myS[p];
#pragma unroll 1
        for (unsigned base = 0; base < wc; base += 64u) {
            unsigned t = base + lane;
            bool inb = t < wc;
            unsigned q = ((unsigned)p + 1u + t) & (E_N - 1u);
            float aq = angS[q];
            float df = aq - ap;
            float fa = (df >= 0.0f) ? df : df + PI_F;
            float da = fabsf(df);
            float circ = fminf(da, PI_F - da);
            bool own = (fa == 0.0f) ? (q > (unsigned)p) : (fa < 1.0f);
            bool act = inb && (circ <= ATH) && own;
            unsigned oq = origS[q];
            // line from the lower ORIGINAL index (reference asymmetry)
            float d = (op < oq) ? fabsf(pnx * mxS[q] + pny * myS[q] - pc)
                                : fabsf(nxS[q] * pmx + nyS[q] * pmy - cS[q]);
            unsigned long long m = __ballot(act);
            if (m) {
                unsigned cnt = (unsigned)__popcll(m);
                unsigned bpos = 0;
                if (lane == 0) bpos = atomicAdd(&ctl[0], cnt);
                bpos = __shfl(bpos, 0, 64);
                unsigned off = (unsigned)__popcll(m & ((1ull << lane) - 1ull));
                if (act) { unsigned idx = bpos + off; if (idx < DBMAX) dbuf[idx] = d; }
            }
        }
    }
    __threadfence();
    __syncthreads();
    if (tid == 0) {
        unsigned tk = atomicAdd(&ctl[1], 1u);
        s_last = (tk == gridDim.x - 1u) ? 1u : 0u;
    }
    __syncthreads();
    if (!s_last) return;
    __threadfence();   // acquire other blocks' dbuf writes

    // ---- epilogue (last block): two-level quantile selection over dbuf -----
    unsigned n = ctl[0]; if (n > DBMAX) n = DBMAX;
    float* stf = (float*)ctl;
    if (n == 0) { if (tid == 0) { stf[4] = 0.0f; stf[5] = 0.0f; } return; }
    long long q1 = (long long)(n / 4) - 1; if (q1 < 0) q1 = 0;
    long long q3 = (3LL * (long long)n) / 4;
    if (q3 > (long long)n - 1) q3 = (long long)n - 1;
    unsigned rks[3] = { (unsigned)q1, n / 2, (unsigned)q3 };

    for (int k = tid; k < NBH; k += 512) s_hist[k] = 0u;
    __syncthreads();
    for (unsigned k = tid; k < n; k += 512u) {
        int b = (int)(dbuf[k] * SCALEH); if (b > NBH - 1) b = NBH - 1;
        atomicAdd(&s_hist[b], 1u);
    }
    __syncthreads();
    {   // scan 8192 bins (512 threads x 16), locate target bins + in-bin ranks
        unsigned loc[16], ss = 0;
#pragma unroll
        for (int k2 = 0; k2 < 16; ++k2) { loc[k2] = s_hist[tid * 16 + k2]; ss += loc[k2]; }
        s_tmp[tid] = ss;
        __syncthreads();
        for (int off = 1; off < 512; off <<= 1) {
            unsigned v = (tid >= off) ? s_tmp[tid - off] : 0u;
            __syncthreads();
            s_tmp[tid] += v;
            __syncthreads();
        }
        unsigned excl = s_tmp[tid] - ss;
        for (int t2 = 0; t2 < 3; ++t2) {
            unsigned r = rks[t2];
            if (r >= excl && r < excl + ss) {
                unsigned cum = excl;
#pragma unroll
                for (int k2 = 0; k2 < 16; ++k2) {
                    unsigned c2 = cum + loc[k2];
                    if (r < c2) { s_info[t2] = (unsigned)(tid * 16 + k2); s_info[3 + t2] = r - cum; break; }
                    cum = c2;
                }
            }
        }
    }
    __syncthreads();
    int tb0 = (int)s_info[0], tb1 = (int)s_info[1], tb2 = (int)s_info[2];
    for (int k = tid; k < 3 * NBS; k += 512) s_sub[k] = 0u;
    __syncthreads();
    for (unsigned k = tid; k < n; k += 512u) {
        float d = dbuf[k];
        int b = (int)(d * SCALEH); if (b > NBH - 1) b = NBH - 1;
        if (b == tb0 || b == tb1 || b == tb2) {
            float lo = (float)b * WH;
            int sb = (int)((d - lo) * SCALES);
            sb = sb < 0 ? 0 : (sb > NBS - 1 ? NBS - 1 : sb);
            if (b == tb0) atomicAdd(&s_sub[sb], 1u);
            if (b == tb1) atomicAdd(&s_sub[NBS + sb], 1u);
            if (b == tb2) atomicAdd(&s_sub[2 * NBS + sb], 1u);
        }
    }
    __syncthreads();
    for (int t2 = 0; t2 < 3; ++t2) {   // scan 1024 sub-bins (512 x 2)
        unsigned l0 = s_sub[t2 * NBS + 2 * tid], l1 = s_sub[t2 * NBS + 2 * tid + 1];
        unsigned ss = l0 + l1;
        s_tmp[tid] = ss;
        __syncthreads();
        for (int off = 1; off < 512; off <<= 1) {
            unsigned v = (tid >= off) ? s_tmp[tid - off] : 0u;
            __syncthreads();
            s_tmp[tid] += v;
            __syncthreads();
        }
        unsigned total = s_tmp[511];
        unsigned excl = s_tmp[tid] - ss;
        unsigned r = s_info[3 + t2];
        if (total == 0) {
            if (tid == 0) s_vv[t2] = (float)s_info[t2] * WH + 0.5f * WH;
        } else {
            if (r >= total) r = total - 1;
            if (r >= excl && r < excl + ss) {
                int sb = (r < excl + l0) ? (2 * tid) : (2 * tid + 1);
                s_vv[t2] = (float)s_info[t2] * WH + ((float)sb + 0.5f) * WS2;
            }
        }
        __syncthreads();
    }
    if (tid == 0) {
        float iqr = fmaxf(s_vv[2] - s_vv[0], 1e-6f);
        stf[4] = s_vv[1];          // mu
        stf[5] = 0.75f * iqr;      // margin = iqr * 0.5 * 1.5
    }
}

// ---- K4: hinge sum over dbuf; last block writes the loss -------------------
__global__ __launch_bounds__(256) void hinge(char* __restrict__ ws,
                                             unsigned* __restrict__ out)
{
    unsigned* ctl = (unsigned*)(ws + O_CTL);
    const float* stf = (const float*)ctl;
    double* gsum = (double*)(ws + O_CTL + 32);
    const float* dbuf = (const float*)(ws + O_DBUF);
    unsigned n = ctl[0]; if (n > DBMAX) n = DBMAX;
    float mu = stf[4], margin = stf[5];
    int tid = threadIdx.x, bid = blockIdx.x;
    int w = tid >> 6, lane = tid & 63;
    double acc = 0.0;
    for (unsigned k = (unsigned)bid * 256u + tid; k < n; k += 65536u) {
        float d = dbuf[k];
        acc += (double)fmaxf(fabsf(d - mu) - margin, 0.0f);
    }
    for (int off = 32; off > 0; off >>= 1) acc += __shfl_down(acc, off, 64);
    __shared__ double s_w[4];
    __shared__ unsigned s_last;
    if (lane == 0) s_w[w] = acc;
    __syncthreads();
    if (tid == 0) {
        double part = s_w[0] + s_w[1] + s_w[2] + s_w[3];
        atomicAdd(gsum, part);
        __threadfence();
        unsigned tk = atomicAdd(&ctl[2], 1u);
        s_last = (tk == gridDim.x - 1u) ? 1u : 0u;
    }
    __syncthreads();
    if (tid == 0 && s_last) {
        __threadfence();
        double denom = n ? (double)n : 1.0;
        float loss = (float)(gsum[0] / denom);
        __hip_bfloat16 h = __float2bfloat16(loss);
        unsigned short b = *(unsigned short*)&h;
        out[0] = ((unsigned)b << 16) | (unsigned)b;   // dtype-hedged scalar write
    }
}

// ============================== launcher ====================================
extern "C" void kernel_launch(void* const* d_in, const int* in_sizes, int n_in,
                              void* d_out, int out_size, void* d_ws, size_t ws_size,
                              hipStream_t stream) {
    const void* pos = d_in[0];
    const int* eidx = (const int*)d_in[2];   // adjacency (d_in[1]) unused
    char* ws = (char*)d_ws;
    unsigned* outp = (unsigned*)d_out;

    prep<<<16, 256, 0, stream>>>(pos, eidx, ws);
    sortk<<<1, 1024, 0, stream>>>(ws);
    sweep<<<256, 512, 0, stream>>>(ws);
    hinge<<<256, 256, 0, stream>>>(ws, outp);
}

// Round 7
// 191.951 us; speedup vs baseline: 3.4365x; 3.4365x over previous
//
#include <hip/hip_runtime.h>
#include <hip/hip_bf16.h>
#include <math.h>

#define E_N 4096
#define PI_F 3.14159265358979323846f
#define ATH 0.08726646259971647f   /* radians(5.0) */

// angle counting-sort bins
#define AB_N 2048
#define AB_SCALE 651.8986469f      /* 2048/pi */
#define BWINP1 60                  /* window [p+1, bstart[bin+60]); ceil(ATH*scale)=57 +3 margin */

// distance selection: coarse 2048 bins over [0,160), sub 2048 -> res 3.8e-5 (r4-proven)
#define NB1 2048
#define SCALE1 12.8f
#define W1 0.078125f
#define NB2 2048
#define SCALE2 26214.4f            /* NB2 / W1 */
#define W2 (W1 / (float)NB2)

// workspace layout (bytes); ws >= 256 MiB
#define O_SANG 0          /* sorted-order per-edge attrs: 4096 f32 each */
#define O_SNX  16384
#define O_SNY  32768
#define O_SC   49152
#define O_SMX  65536
#define O_SMY  81920
#define O_SORG 98304      /* 4096 u32 sorted slot -> original edge */
#define O_BST  114688     /* 2048 u32 angle-bin starts */
#define O_H1   122880     /* 2048 u32 coarse hist */
#define O_H2   131072     /* 3*2048 u32 sub hists */
#define O_CTL  155648     /* 4096 B control block (zeroed by init_sort) */
#define O_DBUF 262144     /* 8 segments x SEGCAP floats */
#define SEGCAP (1u << 20)
#define NSEG 8

// ctl u32 indices: [0]=ticket_sweep [1]=ticket_hinge [2]=n [3]=ticket_selB
// [4..6]=target coarse bins [7..9]=rank-in-bin  f[10]=mu f[11]=margin
// [14..15]=gsum (double, byte offset 56, 8-aligned)
// segment cursors: u32 at O_CTL + 1024 + s*256 (separate cache lines)

__device__ __forceinline__ int bin_of(float a) {
    int b = (int)(a * AB_SCALE);
    return b < 0 ? 0 : (b > AB_N - 1 ? AB_N - 1 : b);
}
__device__ __forceinline__ unsigned* segcur_ptr(char* ws, int s) {
    return (unsigned*)(ws + O_CTL + 1024 + s * 256);
}

// ---- K1: fused dtype-detect + geometry + counting sort (1 x 1024) ----------
// Scatters attributes directly into sorted order; zeroes ctl/h1/h2.
__global__ __launch_bounds__(1024) void init_sort(const void* __restrict__ posv,
                                                  const int* __restrict__ eidx,
                                                  char* __restrict__ ws)
{
    float* angS = (float*)(ws + O_SANG);
    float* nxS  = (float*)(ws + O_SNX);
    float* nyS  = (float*)(ws + O_SNY);
    float* cS   = (float*)(ws + O_SC);
    float* mxS  = (float*)(ws + O_SMX);
    float* myS  = (float*)(ws + O_SMY);
    unsigned* origS = (unsigned*)(ws + O_SORG);
    unsigned* bst   = (unsigned*)(ws + O_BST);
    unsigned* h1    = (unsigned*)(ws + O_H1);
    unsigned* h2    = (unsigned*)(ws + O_H2);
    unsigned* ctl   = (unsigned*)(ws + O_CTL);

    __shared__ unsigned cnt[AB_N];
    __shared__ unsigned scn[1024];
    __shared__ unsigned flag;
    int tid = threadIdx.x;
    if (tid == 0) flag = 0u;
    cnt[tid] = 0u; cnt[tid + 1024] = 0u;
    // zero control + hists (ctl block incl. segment cursors & gsum)
    ctl[tid] = 0u;
    h1[tid] = 0u; h1[tid + 1024] = 0u;
    for (int k = tid; k < 3 * NB2; k += 1024) h2[k] = 0u;
    __syncthreads();

    // dtype detect: f32 misread as bf16 halves shows exponents >=137 (|v|>=1024)
    {
        const unsigned short* ph = (const unsigned short*)posv;
        unsigned f = 0;
#pragma unroll
        for (int k = 0; k < 8; ++k) {
            unsigned short v = ph[tid + k * 1024];
            if (((v >> 7) & 0xFFu) >= 137u) f = 1u;
        }
        if (f) atomicOr(&flag, 1u);
    }
    __syncthreads();
    bool isf32 = (flag != 0u);

    // per-edge geometry in registers + angle-bin count
    float rang[4], rnx[4], rny[4], rc[4], rmx[4], rmy[4];
    int lb[4];
#pragma unroll
    for (int k = 0; k < 4; ++k) {
        int e = tid + k * 1024;
        int s = eidx[e], d = eidx[E_N + e];
        float px, py, qx, qy;
        if (isf32) {
            const float* pf = (const float*)posv;
            px = pf[2*s]; py = pf[2*s+1]; qx = pf[2*d]; qy = pf[2*d+1];
        } else {
            const __hip_bfloat16* pb = (const __hip_bfloat16*)posv;
            px = __bfloat162float(pb[2*s]); py = __bfloat162float(pb[2*s+1]);
            qx = __bfloat162float(pb[2*d]); qy = __bfloat162float(pb[2*d+1]);
        }
        float vx = qx - px, vy = qy - py;
        float len = fmaxf(sqrtf(vx*vx + vy*vy), 1e-8f);
        float dx = vx / len, dy = vy / len;
        float a = fmodf(atan2f(dy, dx), PI_F);
        if (a < 0.0f) a += PI_F;          // python floor-mod -> [0, pi)
        rang[k] = a; rnx[k] = -dy; rny[k] = dx;
        rc[k]  = px * (-dy) + py * dx;
        rmx[k] = (px + qx) * 0.5f;
        rmy[k] = (py + qy) * 0.5f;
        int b = bin_of(a);
        lb[k] = b;
        atomicAdd(&cnt[b], 1u);
    }
    __syncthreads();
    // exclusive scan over 2048 bins
    unsigned c0 = cnt[2*tid], c1 = cnt[2*tid+1], s2 = c0 + c1;
    scn[tid] = s2;
    __syncthreads();
    for (int off = 1; off < 1024; off <<= 1) {
        unsigned v = (tid >= off) ? scn[tid - off] : 0u;
        __syncthreads();
        scn[tid] += v;
        __syncthreads();
    }
    unsigned excl = scn[tid] - s2;
    bst[2*tid] = excl; bst[2*tid+1] = excl + c0;
    cnt[2*tid] = excl; cnt[2*tid+1] = excl + c0;   // reuse as cursors
    __syncthreads();
    // scatter into sorted-order arrays (order within bin arbitrary)
#pragma unroll
    for (int k = 0; k < 4; ++k) {
        int e = tid + k * 1024;
        unsigned pos = atomicAdd(&cnt[lb[k]], 1u);
        angS[pos] = rang[k]; nxS[pos] = rnx[k]; nyS[pos] = rny[k];
        cS[pos] = rc[k]; mxS[pos] = rmx[k]; myS[pos] = rmy[k];
        origS[pos] = (unsigned)e;
    }
}

// ---- K2: window sweep -> LDS-staged compaction + per-block coarse hist -----
// Last block (ticket) scans h1 and publishes n / target bins / in-bin ranks.
#define STAGE_CAP 8192
__global__ __launch_bounds__(512) void sweep(char* __restrict__ ws)
{
    float* angS = (float*)(ws + O_SANG);
    float* nxS  = (float*)(ws + O_SNX);
    float* nyS  = (float*)(ws + O_SNY);
    float* cS   = (float*)(ws + O_SC);
    float* mxS  = (float*)(ws + O_SMX);
    float* myS  = (float*)(ws + O_SMY);
    unsigned* origS = (unsigned*)(ws + O_SORG);
    unsigned* bst   = (unsigned*)(ws + O_BST);
    unsigned* h1    = (unsigned*)(ws + O_H1);
    unsigned* ctl   = (unsigned*)(ws + O_CTL);
    float* dbuf     = (float*)(ws + O_DBUF);

    __shared__ unsigned s_bst[AB_N];       // 8KB
    __shared__ float    s_stage[STAGE_CAP];// 32KB
    __shared__ unsigned s_h1[NB1];         // 8KB
    __shared__ unsigned s_tmp[512];        // 2KB (epilogue)
    __shared__ unsigned s_cnt, s_g, s_last;

    int tid = threadIdx.x, bid = blockIdx.x;
    int w = tid >> 6, lane = tid & 63;
    int seg = bid & (NSEG - 1);
    unsigned* scur = segcur_ptr(ws, seg);
    float* segbuf = dbuf + (size_t)seg * SEGCAP;

    for (int k = tid; k < AB_N; k += 512) s_bst[k] = bst[k];
    for (int k = tid; k < NB1;  k += 512) s_h1[k] = 0u;
    if (tid == 0) s_cnt = 0u;
    __syncthreads();

#pragma unroll 1
    for (int i = 0; i < 2; ++i) {
        int p = bid * 16 + i * 8 + w;
        float ap = angS[p];
        int bw = bin_of(ap) + BWINP1; if (bw >= AB_N) bw -= AB_N;
        unsigned wc = (s_bst[bw] + E_N - 1u - (unsigned)p) & (E_N - 1u);
        unsigned op = origS[p];
        float pnx = nxS[p], pny = nyS[p], pc = cS[p];
        float pmx = mxS[p], pmy = myS[p];
#pragma unroll 1
        for (unsigned base = 0; base < wc; base += 64u) {
            unsigned t = base + lane;
            bool inb = t < wc;
            unsigned q = ((unsigned)p + 1u + t) & (E_N - 1u);
            float aq = angS[q];
            float df = aq - ap;
            float fa = (df >= 0.0f) ? df : df + PI_F;
            float da = fabsf(df);
            float circ = fminf(da, PI_F - da);
            bool own = (fa == 0.0f) ? (q > (unsigned)p) : (fa < 1.0f);
            bool act = inb && (circ <= ATH) && own;
            unsigned oq = origS[q];
            // line from the lower ORIGINAL index (reference asymmetry)
            float d = (op < oq) ? fabsf(pnx * mxS[q] + pny * myS[q] - pc)
                                : fabsf(nxS[q] * pmx + nyS[q] * pmy - cS[q]);
            unsigned long long m = __ballot(act);
            if (m) {
                unsigned cw = (unsigned)__popcll(m);
                unsigned lpos = 0;
                if (lane == 0) lpos = atomicAdd(&s_cnt, cw);   // LDS cursor
                lpos = __shfl(lpos, 0, 64);
                unsigned off = (unsigned)__popcll(m & ((1ull << lane) - 1ull));
                if (act) {
                    unsigned idx = lpos + off;
                    if (idx < STAGE_CAP) s_stage[idx] = d;
                    int b = (int)(d * SCALE1); if (b > NB1 - 1) b = NB1 - 1;
                    atomicAdd(&s_h1[b], 1u);
                }
            }
        }
        // block flush: one global atomic per flush, coalesced copy
        __syncthreads();
        unsigned cblk = s_cnt; if (cblk > STAGE_CAP) cblk = STAGE_CAP;
        if (cblk) {
            if (tid == 0) s_g = atomicAdd(scur, cblk);
            __syncthreads();
            unsigned g = s_g;
            for (unsigned k = tid; k < cblk; k += 512u) {
                unsigned idx = g + k;
                if (idx < SEGCAP) segbuf[idx] = s_stage[k];
            }
        }
        __syncthreads();
        if (tid == 0) s_cnt = 0u;
        __syncthreads();
    }
    // flush per-block coarse hist (nonzero-guarded, wave-coalesced)
    for (int k = tid; k < NB1; k += 512) {
        unsigned v = s_h1[k];
        if (v) atomicAdd(&h1[k], v);
    }
    __threadfence();
    __syncthreads();
    if (tid == 0) {
        unsigned tk = atomicAdd(&ctl[0], 1u);
        s_last = (tk == gridDim.x - 1u) ? 1u : 0u;
    }
    __syncthreads();
    if (!s_last) return;
    __threadfence();   // acquire all blocks' h1 + cursors

    // ---- epilogue: n, ranks, coarse target bins (2048-bin scan only) -------
    unsigned n = 0;
    for (int s = 0; s < NSEG; ++s) {
        unsigned c = *segcur_ptr(ws, s);
        n += (c > SEGCAP ? SEGCAP : c);
    }
    if (tid == 0) ctl[2] = n;
    if (n == 0) return;
    long long q1 = (long long)(n / 4) - 1; if (q1 < 0) q1 = 0;
    long long q3 = (3LL * (long long)n) / 4;
    if (q3 > (long long)n - 1) q3 = (long long)n - 1;
    unsigned rks[3] = { (unsigned)q1, n / 2, (unsigned)q3 };

    unsigned loc[4], ss = 0;
#pragma unroll
    for (int k = 0; k < 4; ++k) { loc[k] = h1[tid * 4 + k]; ss += loc[k]; }
    s_tmp[tid] = ss;
    __syncthreads();
    for (int off = 1; off < 512; off <<= 1) {
        unsigned v = (tid >= off) ? s_tmp[tid - off] : 0u;
        __syncthreads();
        s_tmp[tid] += v;
        __syncthreads();
    }
    unsigned excl = s_tmp[tid] - ss;
    for (int t = 0; t < 3; ++t) {
        unsigned r = rks[t];
        if (r >= excl && r < excl + ss) {
            unsigned cum = excl;
#pragma unroll
            for (int k = 0; k < 4; ++k) {
                unsigned c2 = cum + loc[k];
                if (r < c2) { ctl[4 + t] = (unsigned)(tid * 4 + k); ctl[7 + t] = r - cum; break; }
                cum = c2;
            }
        }
    }
}

// ---- K3: sub-histograms over dbuf slices (32 x 512); last block -> mu/margin
__global__ __launch_bounds__(512) void selB(char* __restrict__ ws)
{
    unsigned* ctl = (unsigned*)(ws + O_CTL);
    unsigned* h2  = (unsigned*)(ws + O_H2);
    const float* dbuf = (const float*)(ws + O_DBUF);

    __shared__ unsigned s_sub[3 * NB2];   // 24KB
    __shared__ unsigned s_tmp[512];
    __shared__ float    s_vv[3];
    __shared__ unsigned s_last;

    int tid = threadIdx.x, bid = blockIdx.x;
    int tb0 = (int)ctl[4], tb1 = (int)ctl[5], tb2 = (int)ctl[6];
    for (int k = tid; k < 3 * NB2; k += 512) s_sub[k] = 0u;
    __syncthreads();

    for (int s = 0; s < NSEG; ++s) {
        unsigned c = *segcur_ptr(ws, s); if (c > SEGCAP) c = SEGCAP;
        const float* segbuf = dbuf + (size_t)s * SEGCAP;
        for (unsigned k = (unsigned)bid * 512u + tid; k < c; k += 32u * 512u) {
            float d = segbuf[k];
            int b = (int)(d * SCALE1); if (b > NB1 - 1) b = NB1 - 1;
            if (b == tb0 || b == tb1 || b == tb2) {
                float lo = (float)b * W1;
                int sb = (int)((d - lo) * SCALE2);
                sb = sb < 0 ? 0 : (sb > NB2 - 1 ? NB2 - 1 : sb);
                if (b == tb0) atomicAdd(&s_sub[sb], 1u);
                if (b == tb1) atomicAdd(&s_sub[NB2 + sb], 1u);
                if (b == tb2) atomicAdd(&s_sub[2 * NB2 + sb], 1u);
            }
        }
    }
    __syncthreads();
    for (int k = tid; k < 3 * NB2; k += 512) {
        unsigned v = s_sub[k];
        if (v) atomicAdd(&h2[k], v);
    }
    __threadfence();
    __syncthreads();
    if (tid == 0) {
        unsigned tk = atomicAdd(&ctl[3], 1u);
        s_last = (tk == gridDim.x - 1u) ? 1u : 0u;
    }
    __syncthreads();
    if (!s_last) return;
    __threadfence();

    for (int t = 0; t < 3; ++t) {
        unsigned loc[4], ss = 0;
#pragma unroll
        for (int k = 0; k < 4; ++k) { loc[k] = h2[t * NB2 + tid * 4 + k]; ss += loc[k]; }
        s_tmp[tid] = ss;
        __syncthreads();
        for (int off = 1; off < 512; off <<= 1) {
            unsigned v = (tid >= off) ? s_tmp[tid - off] : 0u;
            __syncthreads();
            s_tmp[tid] += v;
            __syncthreads();
        }
        unsigned total = s_tmp[511];
        unsigned excl = s_tmp[tid] - ss;
        unsigned r = ctl[7 + t];
        if (total == 0) {
            if (tid == 0) s_vv[t] = (float)ctl[4 + t] * W1 + 0.5f * W1;
        } else {
            if (r >= total) r = total - 1;
            if (r >= excl && r < excl + ss) {
                unsigned cum = excl;
#pragma unroll
                for (int k = 0; k < 4; ++k) {
                    unsigned c2 = cum + loc[k];
                    if (r < c2) {
                        s_vv[t] = (float)ctl[4 + t] * W1 + ((float)(tid * 4 + k) + 0.5f) * W2;
                        break;
                    }
                    cum = c2;
                }
            }
        }
        __syncthreads();
    }
    if (tid == 0) {
        float* stf = (float*)ctl;
        float iqr = fmaxf(s_vv[2] - s_vv[0], 1e-6f);
        stf[10] = s_vv[1];          // mu
        stf[11] = 0.75f * iqr;      // margin = iqr * 0.5 * 1.5
    }
}

// ---- K4: hinge sum over dbuf (64 x 256); last block writes the loss --------
__global__ __launch_bounds__(256) void hinge(char* __restrict__ ws,
                                             unsigned* __restrict__ out)
{
    unsigned* ctl = (unsigned*)(ws + O_CTL);
    const float* stf = (const float*)ctl;
    double* gsum = (double*)(ws + O_CTL + 56);
    const float* dbuf = (const float*)(ws + O_DBUF);
    unsigned n = ctl[2];
    float mu = stf[10], margin = stf[11];
    int tid = threadIdx.x, bid = blockIdx.x;
    int w = tid >> 6, lane = tid & 63;
    double acc = 0.0;
    for (int s = 0; s < NSEG; ++s) {
        unsigned c = *segcur_ptr(ws, s); if (c > SEGCAP) c = SEGCAP;
        const float* segbuf = dbuf + (size_t)s * SEGCAP;
        for (unsigned k = (unsigned)bid * 256u + tid; k < c; k += 64u * 256u) {
            float d = segbuf[k];
            acc += (double)fmaxf(fabsf(d - mu) - margin, 0.0f);
        }
    }
    for (int off = 32; off > 0; off >>= 1) acc += __shfl_down(acc, off, 64);
    __shared__ double s_w[4];
    __shared__ unsigned s_last;
    if (lane == 0) s_w[w] = acc;
    __syncthreads();
    if (tid == 0) {
        double part = s_w[0] + s_w[1] + s_w[2] + s_w[3];
        atomicAdd(gsum, part);
        __threadfence();
        unsigned tk = atomicAdd(&ctl[1], 1u);
        s_last = (tk == gridDim.x - 1u) ? 1u : 0u;
    }
    __syncthreads();
    if (tid == 0 && s_last) {
        __threadfence();
        double denom = n ? (double)n : 1.0;
        float loss = (float)(gsum[0] / denom);
        __hip_bfloat16 h = __float2bfloat16(loss);
        unsigned short b = *(unsigned short*)&h;
        out[0] = ((unsigned)b << 16) | (unsigned)b;   // dtype-hedged scalar write
    }
}

// ============================== launcher ====================================
extern "C" void kernel_launch(void* const* d_in, const int* in_sizes, int n_in,
                              void* d_out, int out_size, void* d_ws, size_t ws_size,
                              hipStream_t stream) {
    const void* pos = d_in[0];
    const int* eidx = (const int*)d_in[2];   // adjacency (d_in[1]) unused
    char* ws = (char*)d_ws;
    unsigned* outp = (unsigned*)d_out;

    init_sort<<<1, 1024, 0, stream>>>(pos, eidx, ws);
    sweep<<<256, 512, 0, stream>>>(ws);
    selB<<<32, 512, 0, stream>>>(ws);
    hinge<<<64, 256, 0, stream>>>(ws, outp);
}